// Round 10
// baseline (963.441 us; speedup 1.0000x reference)
//
#include <hip/hip_runtime.h>
#include <hip/hip_bf16.h>

#define NB 4096
#define NS 32
#define NI 16
#define NH 32

typedef float f32x2 __attribute__((ext_vector_type(2)));

// Wave-local LDS write->read turnaround: drain lgkm, fence the compiler.
__device__ __forceinline__ void fence() {
    __builtin_amdgcn_wave_barrier();
    asm volatile("s_waitcnt lgkmcnt(0)" ::: "memory");
    __builtin_amdgcn_wave_barrier();
}

// Cross-half sum via the compiler-known permlane builtin (hazard-safe, VALU).
__device__ __forceinline__ float xhsum(float x) {
    auto p = __builtin_amdgcn_permlane32_swap(
        (int)__float_as_uint(x), (int)__float_as_uint(x), false, false);
    return __uint_as_float((unsigned)p[0]) + __uint_as_float((unsigned)p[1]);
}

__device__ __forceinline__ f32x2 pkfma(f32x2 a, f32x2 b, f32x2 c) {
    return __builtin_elementwise_fma(a, b, c);   // v_pk_fma_f32 on gfx950
}

// R9 proved: named f32x2 weights + pinned waves_per_eu -> no AGPR parking,
// no scratch (WRITE 806MB -> 32B), VGPR=112. R10: live set 112 <= 128, so
// pin 4 waves/EU (budget 128) to double latency hiding on the ode_f
// LDS-turnaround chain (counters showed ~60% VALU idle at 2 waves/EU).
__global__ void __launch_bounds__(256)
__attribute__((amdgpu_waves_per_eu(4, 4)))
odernn_kernel(
    const float* __restrict__ x,    // (B,S,I)
    const float* __restrict__ t,    // (B,S)
    const float* __restrict__ gWih, // (96,16)
    const float* __restrict__ gWhh, // (96,32)
    const float* __restrict__ gbih, // (96)
    const float* __restrict__ gbhh, // (96)
    const float* __restrict__ oW1,  // (64,32)
    const float* __restrict__ ob1,  // (64)
    const float* __restrict__ oW2,  // (32,64)
    const float* __restrict__ ob2,  // (32)
    const float* __restrict__ oW3,  // (32,32)
    const float* __restrict__ ob3,  // (32)
    const float* __restrict__ fW1,  // (64,32)
    const float* __restrict__ fb1,  // (64)
    const float* __restrict__ fW2,  // (1,64)
    const float* __restrict__ fb2,  // (1)
    float* __restrict__ outp)       // (B,1)
{
    const int tid  = threadIdx.x;
    const int lane = tid & 63;
    const int wid  = tid >> 6;
    const int b    = blockIdx.x * 4 + wid;
    const int r    = lane & 31;     // row within half-wave
    const int hf   = lane >> 5;     // half index

    // ---- LDS: GRU weights (col-major [col][32 rows]; lane r -> bank r) ----
    __shared__ float sWr[48 * 32];   // r-gate, cat = [x(16); h(32)]
    __shared__ float sWz[48 * 32];   // z-gate
    __shared__ float sWnh[32 * 32];  // n-gate, h part
    __shared__ float sWni[16 * 32];  // n-gate, x part
    __shared__ __align__(16) float buf[4][64];   // per-wave broadcast buffer

    for (int i = tid; i < 48 * 32; i += 256) {
        int c = i >> 5, r0 = i & 31;
        sWr[i] = (c < 16) ? gWih[r0 * 16 + c]        : gWhh[r0 * 32 + (c - 16)];
        sWz[i] = (c < 16) ? gWih[(32 + r0) * 16 + c] : gWhh[(32 + r0) * 32 + (c - 16)];
    }
    for (int i = tid; i < 32 * 32; i += 256) {
        int c = i >> 5, r0 = i & 31;
        sWnh[i] = gWhh[(64 + r0) * 32 + c];
    }
    for (int i = tid; i < 16 * 32; i += 256) {
        int c = i >> 5, r0 = i & 31;
        sWni[i] = gWih[(64 + r0) * 16 + c];
    }
    __syncthreads();

    float* bufw = buf[wid];
    const float4* bb = reinterpret_cast<const float4*>(bufw);

    // ------- ODE MLP weights -> NAMED per-lane f32x2 registers -------
    f32x2 w1_0, w1_1, w1_2, w1_3, w1_4, w1_5, w1_6, w1_7,
          w1_8, w1_9, w1_10, w1_11, w1_12, w1_13, w1_14, w1_15;
    f32x2 w2_0, w2_1, w2_2, w2_3, w2_4, w2_5, w2_6, w2_7,
          w2_8, w2_9, w2_10, w2_11, w2_12, w2_13, w2_14, w2_15;
    f32x2 w3_0, w3_1, w3_2, w3_3, w3_4, w3_5, w3_6, w3_7;
    {
        const float4* p1 = reinterpret_cast<const float4*>(oW1) + lane * 8;
        float4 v;
#define LD2(i, dA, dB) { v = p1[i]; dA = f32x2{v.x, v.y}; dB = f32x2{v.z, v.w}; }
        LD2(0, w1_0,  w1_1)  LD2(1, w1_2,  w1_3)
        LD2(2, w1_4,  w1_5)  LD2(3, w1_6,  w1_7)
        LD2(4, w1_8,  w1_9)  LD2(5, w1_10, w1_11)
        LD2(6, w1_12, w1_13) LD2(7, w1_14, w1_15)
#undef LD2
        const float4* p2 = reinterpret_cast<const float4*>(oW2) + r * 16 + hf * 8;
#define LD2(i, dA, dB) { v = p2[i]; dA = f32x2{v.x, v.y}; dB = f32x2{v.z, v.w}; }
        LD2(0, w2_0,  w2_1)  LD2(1, w2_2,  w2_3)
        LD2(2, w2_4,  w2_5)  LD2(3, w2_6,  w2_7)
        LD2(4, w2_8,  w2_9)  LD2(5, w2_10, w2_11)
        LD2(6, w2_12, w2_13) LD2(7, w2_14, w2_15)
#undef LD2
        const float4* p3 = reinterpret_cast<const float4*>(oW3) + r * 8 + hf * 4;
#define LD2(i, dA, dB) { v = p3[i]; dA = f32x2{v.x, v.y}; dB = f32x2{v.z, v.w}; }
        LD2(0, w3_0, w3_1)  LD2(1, w3_2, w3_3)
        LD2(2, w3_4, w3_5)  LD2(3, w3_6, w3_7)
#undef LD2
    }
    const float b1r = ob1[lane];
    const float b2r = ob2[r];
    const float b3r = ob3[r];

    const float brr = gbih[r]      + gbhh[r];
    const float bzz = gbih[32 + r] + gbhh[32 + r];
    const float bin = gbih[64 + r];
    const float bhn = gbhh[64 + r];

    // GRU weight LDS base pointers (per-lane, static offsets off these)
    const float* wrp  = &sWr[(hf * 24) * 32 + r];
    const float* wzp  = &sWz[(hf * 24) * 32 + r];
    const float* wnhp = &sWnh[(hf * 16) * 32 + r];
    const float* wnip = &sWni[r];

    // ------- ODE MLP: y (per-lane y[r], dup halves) -> k (same layout) -----
    // Math order identical to R6/R9 (absmax 0.0).
    auto ode_f = [&](float yv) -> float {
        bufw[hf * 32 + r] = yv;     // both halves write y[r]; reads use [0..31]
        fence();
        f32x2 acc1 = f32x2{b1r, 0.0f};
#define S1(kk, wA, wB) { float4 c = bb[kk]; \
        acc1 = pkfma(wA, f32x2{c.x, c.y}, acc1); \
        acc1 = pkfma(wB, f32x2{c.z, c.w}, acc1); }
        S1(0, w1_0,  w1_1)  S1(1, w1_2,  w1_3)
        S1(2, w1_4,  w1_5)  S1(3, w1_6,  w1_7)
        S1(4, w1_8,  w1_9)  S1(5, w1_10, w1_11)
        S1(6, w1_12, w1_13) S1(7, w1_14, w1_15)
#undef S1
        float a1 = fmaxf(acc1.x + acc1.y, 0.0f);
        bufw[lane] = a1;                           // h1 distributed over 64 lanes
        fence();
        f32x2 acc2 = f32x2{0.0f, 0.0f};
        const int o2 = hf * 8;
#define S2(kk, wA, wB) { float4 c = bb[o2 + kk]; \
        acc2 = pkfma(wA, f32x2{c.x, c.y}, acc2); \
        acc2 = pkfma(wB, f32x2{c.z, c.w}, acc2); }
        S2(0, w2_0,  w2_1)  S2(1, w2_2,  w2_3)
        S2(2, w2_4,  w2_5)  S2(3, w2_6,  w2_7)
        S2(4, w2_8,  w2_9)  S2(5, w2_10, w2_11)
        S2(6, w2_12, w2_13) S2(7, w2_14, w2_15)
#undef S2
        float a2 = fmaxf(xhsum(acc2.x + acc2.y) + b2r, 0.0f);
        bufw[hf * 32 + r] = a2;
        fence();
        f32x2 acc3 = f32x2{0.0f, 0.0f};
        const int o3 = hf * 4;
#define S3(kk, wA, wB) { float4 c = bb[o3 + kk]; \
        acc3 = pkfma(wA, f32x2{c.x, c.y}, acc3); \
        acc3 = pkfma(wB, f32x2{c.z, c.w}, acc3); }
        S3(0, w3_0, w3_1)  S3(1, w3_2, w3_3)
        S3(2, w3_4, w3_5)  S3(3, w3_6, w3_7)
#undef S3
        return xhsum(acc3.x + acc3.y) + b3r;
    };

    // ---------- time loop ----------
    float hv = 0.0f;      // hidden carry h[r] (dup halves)
    float outv = 0.0f;    // GRU output out[r] (dup halves)

    #pragma unroll 1
    for (int s = 0; s < NS - 1; ++s) {
        // stage cat = [x_t(16); h(32)] into bufw[0..47]
        const float* xrow = x + ((size_t)b * NS + s) * NI;
        if (hf == 0) {
            bufw[16 + r] = hv;
        } else {
            bufw[r & 15] = xrow[r & 15];   // duplicated writers, same data
        }
        fence();

        // r/z gates: 24 MACs per half each, weights from LDS (bank = r)
        float ar = 0.0f, az = 0.0f;
        #pragma unroll
        for (int kk = 0; kk < 6; ++kk) {
            float4 c = bb[hf*6 + kk];
            ar = fmaf(wrp[(4*kk  )*32], c.x, ar); ar = fmaf(wrp[(4*kk+1)*32], c.y, ar);
            ar = fmaf(wrp[(4*kk+2)*32], c.z, ar); ar = fmaf(wrp[(4*kk+3)*32], c.w, ar);
            az = fmaf(wzp[(4*kk  )*32], c.x, az); az = fmaf(wzp[(4*kk+1)*32], c.y, az);
            az = fmaf(wzp[(4*kk+2)*32], c.z, az); az = fmaf(wzp[(4*kk+3)*32], c.w, az);
        }
        // i_n: x-part (16 cols) — both halves compute FULL sum (dup).
        // h_n: 32 cols, k-split + cross-half sum.
        float in_ = 0.0f, hn = 0.0f;
        #pragma unroll
        for (int kk = 0; kk < 4; ++kk) {
            float4 c = bb[kk];
            in_ = fmaf(wnip[(4*kk  )*32], c.x, in_); in_ = fmaf(wnip[(4*kk+1)*32], c.y, in_);
            in_ = fmaf(wnip[(4*kk+2)*32], c.z, in_); in_ = fmaf(wnip[(4*kk+3)*32], c.w, in_);
        }
        #pragma unroll
        for (int kk = 0; kk < 4; ++kk) {
            float4 c = bb[4 + hf*4 + kk];
            hn = fmaf(wnhp[(4*kk  )*32], c.x, hn); hn = fmaf(wnhp[(4*kk+1)*32], c.y, hn);
            hn = fmaf(wnhp[(4*kk+2)*32], c.z, hn); hn = fmaf(wnhp[(4*kk+3)*32], c.w, hn);
        }
        ar = xhsum(ar) + brr;
        az = xhsum(az) + bzz;
        hn = xhsum(hn) + bhn;
        in_ += bin;

        float rg = 1.0f / (1.0f + __expf(-ar));
        float zg = 1.0f / (1.0f + __expf(-az));
        float ng = tanhf(fmaf(rg, hn, in_));
        outv = (1.0f - zg) * ng + zg * hv;

        hv = outv;
        if (s < NS - 2) {   // final step's ODE integration is dead -> skip
            const float t0 = t[(size_t)b * NS + s];
            const float t1 = t[(size_t)b * NS + s + 1];
            const float ddt = (t1 - t0) * 0.25f;   // dt / n_sub, n_sub = 4
            float hi = outv;
            #pragma unroll 1
            for (int sub = 0; sub < 4; ++sub) {
                float k1 = ode_f(hi);
                float k2 = ode_f(fmaf(ddt, 0.2f * k1, hi));
                float k3 = ode_f(fmaf(ddt, fmaf((float)(9.0/40.0), k2, (float)(3.0/40.0) * k1), hi));
                float k4 = ode_f(fmaf(ddt,
                        fmaf((float)(32.0/9.0), k3,
                        fmaf(-(float)(56.0/15.0), k2, (float)(44.0/45.0) * k1)), hi));
                float k5 = ode_f(fmaf(ddt,
                        fmaf(-(float)(212.0/729.0), k4,
                        fmaf((float)(64448.0/6561.0), k3,
                        fmaf(-(float)(25360.0/2187.0), k2, (float)(19372.0/6561.0) * k1))), hi));
                float k6 = ode_f(fmaf(ddt,
                        fmaf(-(float)(5103.0/18656.0), k5,
                        fmaf((float)(49.0/176.0), k4,
                        fmaf((float)(46732.0/5247.0), k3,
                        fmaf(-(float)(355.0/33.0), k2, (float)(9017.0/3168.0) * k1)))), hi));
                hi = fmaf(ddt,
                        fmaf((float)(11.0/84.0), k6,
                        fmaf(-(float)(2187.0/6784.0), k5,
                        fmaf((float)(125.0/192.0), k4,
                        fmaf((float)(500.0/1113.0), k3, (float)(35.0/384.0) * k1)))), hi);
            }
            hv = hi;
        }
    }

    // ---------- FC head: relu(out @ fW1.T + fb1) @ fW2.T + fb2 ----------
    bufw[hf * 32 + r] = outv;
    fence();
    f32x2 acc = f32x2{fb1[lane], 0.0f};
    {
        const float4* fw = reinterpret_cast<const float4*>(fW1) + lane * 8;
        #pragma unroll
        for (int kk = 0; kk < 8; ++kk) {
            float4 wv = fw[kk];
            float4 c  = bb[kk];
            acc = pkfma(f32x2{wv.x, wv.y}, f32x2{c.x, c.y}, acc);
            acc = pkfma(f32x2{wv.z, wv.w}, f32x2{c.z, c.w}, acc);
        }
    }
    float a = fmaxf(acc.x + acc.y, 0.0f);
    float p = a * fW2[lane];
    #pragma unroll
    for (int m = 1; m < 64; m <<= 1) p += __shfl_xor(p, m, 64);
    if (lane == 0) outp[b] = p + fb2[0];
}

extern "C" void kernel_launch(void* const* d_in, const int* in_sizes, int n_in,
                              void* d_out, int out_size, void* d_ws, size_t ws_size,
                              hipStream_t stream) {
    (void)in_sizes; (void)n_in; (void)d_ws; (void)ws_size; (void)out_size;
    odernn_kernel<<<dim3(NB / 4), dim3(256), 0, stream>>>(
        (const float*)d_in[0],  (const float*)d_in[1],
        (const float*)d_in[2],  (const float*)d_in[3],
        (const float*)d_in[4],  (const float*)d_in[5],
        (const float*)d_in[6],  (const float*)d_in[7],
        (const float*)d_in[8],  (const float*)d_in[9],
        (const float*)d_in[10], (const float*)d_in[11],
        (const float*)d_in[12], (const float*)d_in[13],
        (const float*)d_in[14], (const float*)d_in[15],
        (float*)d_out);
}

// Round 11
// 693.579 us; speedup vs baseline: 1.3891x; 1.3891x over previous
//
#include <hip/hip_runtime.h>
#include <hip/hip_bf16.h>

#define NB 4096
#define NS 32
#define NI 16
#define NH 32

typedef float f32x2 __attribute__((ext_vector_type(2)));

// Wave-local LDS write->read turnaround: drain lgkm, fence the compiler.
__device__ __forceinline__ void fence() {
    __builtin_amdgcn_wave_barrier();
    asm volatile("s_waitcnt lgkmcnt(0)" ::: "memory");
    __builtin_amdgcn_wave_barrier();
}

// Cross-half sum via the compiler-known permlane builtin (hazard-safe, VALU).
__device__ __forceinline__ float xhsum(float x) {
    auto p = __builtin_amdgcn_permlane32_swap(
        (int)__float_as_uint(x), (int)__float_as_uint(x), false, false);
    return __uint_as_float((unsigned)p[0]) + __uint_as_float((unsigned)p[1]);
}

__device__ __forceinline__ f32x2 pkfma(f32x2 a, f32x2 b, f32x2 c) {
    return __builtin_elementwise_fma(a, b, c);   // v_pk_fma_f32 on gfx950
}

// R9 regime (named f32x2 weights + waves_per_eu(2,2)) is the only clean
// allocation point: VGPR=112, zero scratch. R11: 2 batch elements per wave
// (weights shared!) -> fences/elem halve, ILP-2 fills the 60% VALU idle.
// Live ~150 <= 256 budget. (4,4) budget 128 < live -> 2.2GB spill (R10).
__global__ void __launch_bounds__(256)
__attribute__((amdgpu_waves_per_eu(2, 2)))
odernn_kernel(
    const float* __restrict__ x,    // (B,S,I)
    const float* __restrict__ t,    // (B,S)
    const float* __restrict__ gWih, // (96,16)
    const float* __restrict__ gWhh, // (96,32)
    const float* __restrict__ gbih, // (96)
    const float* __restrict__ gbhh, // (96)
    const float* __restrict__ oW1,  // (64,32)
    const float* __restrict__ ob1,  // (64)
    const float* __restrict__ oW2,  // (32,64)
    const float* __restrict__ ob2,  // (32)
    const float* __restrict__ oW3,  // (32,32)
    const float* __restrict__ ob3,  // (32)
    const float* __restrict__ fW1,  // (64,32)
    const float* __restrict__ fb1,  // (64)
    const float* __restrict__ fW2,  // (1,64)
    const float* __restrict__ fb2,  // (1)
    float* __restrict__ outp)       // (B,1)
{
    const int tid  = threadIdx.x;
    const int lane = tid & 63;
    const int wid  = tid >> 6;
    const int b0   = blockIdx.x * 8 + wid * 2;   // this wave's two elements
    const int b1   = b0 + 1;
    const int r    = lane & 31;     // row within half-wave
    const int hf   = lane >> 5;     // half index

    // ---- LDS: GRU weights (col-major [col][32 rows]; lane r -> bank r) ----
    __shared__ float sWr[48 * 32];   // r-gate, cat = [x(16); h(32)]
    __shared__ float sWz[48 * 32];   // z-gate
    __shared__ float sWnh[32 * 32];  // n-gate, h part
    __shared__ float sWni[16 * 32];  // n-gate, x part
    __shared__ __align__(16) float buf[4][2][64];  // per-wave, per-element

    for (int i = tid; i < 48 * 32; i += 256) {
        int c = i >> 5, r0 = i & 31;
        sWr[i] = (c < 16) ? gWih[r0 * 16 + c]        : gWhh[r0 * 32 + (c - 16)];
        sWz[i] = (c < 16) ? gWih[(32 + r0) * 16 + c] : gWhh[(32 + r0) * 32 + (c - 16)];
    }
    for (int i = tid; i < 32 * 32; i += 256) {
        int c = i >> 5, r0 = i & 31;
        sWnh[i] = gWhh[(64 + r0) * 32 + c];
    }
    for (int i = tid; i < 16 * 32; i += 256) {
        int c = i >> 5, r0 = i & 31;
        sWni[i] = gWih[(64 + r0) * 16 + c];
    }
    __syncthreads();

    float* bufw0 = buf[wid][0];
    float* bufw1 = buf[wid][1];
    const float4* bb0 = reinterpret_cast<const float4*>(bufw0);
    const float4* bb1 = reinterpret_cast<const float4*>(bufw1);

    // ------- ODE MLP weights -> NAMED per-lane f32x2 registers (shared) ----
    f32x2 w1_0, w1_1, w1_2, w1_3, w1_4, w1_5, w1_6, w1_7,
          w1_8, w1_9, w1_10, w1_11, w1_12, w1_13, w1_14, w1_15;
    f32x2 w2_0, w2_1, w2_2, w2_3, w2_4, w2_5, w2_6, w2_7,
          w2_8, w2_9, w2_10, w2_11, w2_12, w2_13, w2_14, w2_15;
    f32x2 w3_0, w3_1, w3_2, w3_3, w3_4, w3_5, w3_6, w3_7;
    {
        const float4* p1 = reinterpret_cast<const float4*>(oW1) + lane * 8;
        float4 v;
#define LD2(i, dA, dB) { v = p1[i]; dA = f32x2{v.x, v.y}; dB = f32x2{v.z, v.w}; }
        LD2(0, w1_0,  w1_1)  LD2(1, w1_2,  w1_3)
        LD2(2, w1_4,  w1_5)  LD2(3, w1_6,  w1_7)
        LD2(4, w1_8,  w1_9)  LD2(5, w1_10, w1_11)
        LD2(6, w1_12, w1_13) LD2(7, w1_14, w1_15)
#undef LD2
        const float4* p2 = reinterpret_cast<const float4*>(oW2) + r * 16 + hf * 8;
#define LD2(i, dA, dB) { v = p2[i]; dA = f32x2{v.x, v.y}; dB = f32x2{v.z, v.w}; }
        LD2(0, w2_0,  w2_1)  LD2(1, w2_2,  w2_3)
        LD2(2, w2_4,  w2_5)  LD2(3, w2_6,  w2_7)
        LD2(4, w2_8,  w2_9)  LD2(5, w2_10, w2_11)
        LD2(6, w2_12, w2_13) LD2(7, w2_14, w2_15)
#undef LD2
        const float4* p3 = reinterpret_cast<const float4*>(oW3) + r * 8 + hf * 4;
#define LD2(i, dA, dB) { v = p3[i]; dA = f32x2{v.x, v.y}; dB = f32x2{v.z, v.w}; }
        LD2(0, w3_0, w3_1)  LD2(1, w3_2, w3_3)
        LD2(2, w3_4, w3_5)  LD2(3, w3_6, w3_7)
#undef LD2
    }
    const float b1r = ob1[lane];
    const float b2r = ob2[r];
    const float b3r = ob3[r];

    const float brr = gbih[r]      + gbhh[r];
    const float bzz = gbih[32 + r] + gbhh[32 + r];
    const float bin = gbih[64 + r];
    const float bhn = gbhh[64 + r];

    // GRU weight LDS base pointers (per-lane, static offsets off these)
    const float* wrp  = &sWr[(hf * 24) * 32 + r];
    const float* wzp  = &sWz[(hf * 24) * 32 + r];
    const float* wnhp = &sWnh[(hf * 16) * 32 + r];
    const float* wnip = &sWni[r];

    // --- ODE MLP for BOTH elements; per-element math identical to R9 ---
    auto ode_f2 = [&](float y0, float y1, float& o0, float& o1) {
        bufw0[hf * 32 + r] = y0;
        bufw1[hf * 32 + r] = y1;
        fence();
        f32x2 p0 = f32x2{b1r, 0.0f}, p1a = f32x2{b1r, 0.0f};
#define S1(kk, wA, wB) { float4 c0 = bb0[kk]; float4 c1 = bb1[kk]; \
        p0  = pkfma(wA, f32x2{c0.x, c0.y}, p0);  \
        p0  = pkfma(wB, f32x2{c0.z, c0.w}, p0);  \
        p1a = pkfma(wA, f32x2{c1.x, c1.y}, p1a); \
        p1a = pkfma(wB, f32x2{c1.z, c1.w}, p1a); }
        S1(0, w1_0,  w1_1)  S1(1, w1_2,  w1_3)
        S1(2, w1_4,  w1_5)  S1(3, w1_6,  w1_7)
        S1(4, w1_8,  w1_9)  S1(5, w1_10, w1_11)
        S1(6, w1_12, w1_13) S1(7, w1_14, w1_15)
#undef S1
        float a1_0 = fmaxf(p0.x + p0.y, 0.0f);
        float a1_1 = fmaxf(p1a.x + p1a.y, 0.0f);
        bufw0[lane] = a1_0;
        bufw1[lane] = a1_1;
        fence();
        f32x2 q0 = f32x2{0.0f, 0.0f}, q1 = f32x2{0.0f, 0.0f};
        const int o2 = hf * 8;
#define S2(kk, wA, wB) { float4 c0 = bb0[o2 + kk]; float4 c1 = bb1[o2 + kk]; \
        q0 = pkfma(wA, f32x2{c0.x, c0.y}, q0); \
        q0 = pkfma(wB, f32x2{c0.z, c0.w}, q0); \
        q1 = pkfma(wA, f32x2{c1.x, c1.y}, q1); \
        q1 = pkfma(wB, f32x2{c1.z, c1.w}, q1); }
        S2(0, w2_0,  w2_1)  S2(1, w2_2,  w2_3)
        S2(2, w2_4,  w2_5)  S2(3, w2_6,  w2_7)
        S2(4, w2_8,  w2_9)  S2(5, w2_10, w2_11)
        S2(6, w2_12, w2_13) S2(7, w2_14, w2_15)
#undef S2
        float a2_0 = fmaxf(xhsum(q0.x + q0.y) + b2r, 0.0f);
        float a2_1 = fmaxf(xhsum(q1.x + q1.y) + b2r, 0.0f);
        bufw0[hf * 32 + r] = a2_0;
        bufw1[hf * 32 + r] = a2_1;
        fence();
        f32x2 s0 = f32x2{0.0f, 0.0f}, s1 = f32x2{0.0f, 0.0f};
        const int o3 = hf * 4;
#define S3(kk, wA, wB) { float4 c0 = bb0[o3 + kk]; float4 c1 = bb1[o3 + kk]; \
        s0 = pkfma(wA, f32x2{c0.x, c0.y}, s0); \
        s0 = pkfma(wB, f32x2{c0.z, c0.w}, s0); \
        s1 = pkfma(wA, f32x2{c1.x, c1.y}, s1); \
        s1 = pkfma(wB, f32x2{c1.z, c1.w}, s1); }
        S3(0, w3_0, w3_1)  S3(1, w3_2, w3_3)
        S3(2, w3_4, w3_5)  S3(3, w3_6, w3_7)
#undef S3
        o0 = xhsum(s0.x + s0.y) + b3r;
        o1 = xhsum(s1.x + s1.y) + b3r;
    };

    // ---------- time loop ----------
    float hv0 = 0.0f, hv1 = 0.0f;       // hidden carries h[r] (dup halves)
    float outv0 = 0.0f, outv1 = 0.0f;   // GRU outputs

    #pragma unroll 1
    for (int s = 0; s < NS - 1; ++s) {
        const float* xrow0 = x + ((size_t)b0 * NS + s) * NI;
        const float* xrow1 = x + ((size_t)b1 * NS + s) * NI;
        if (hf == 0) {
            bufw0[16 + r] = hv0;
            bufw1[16 + r] = hv1;
        } else {
            bufw0[r & 15] = xrow0[r & 15];
            bufw1[r & 15] = xrow1[r & 15];
        }
        fence();

        // r/z gates: weight loaded ONCE, used for both elements (ILP-2)
        float ar0 = 0.f, ar1 = 0.f, az0 = 0.f, az1 = 0.f;
        #pragma unroll
        for (int kk = 0; kk < 6; ++kk) {
            float4 c0 = bb0[hf*6 + kk];
            float4 c1 = bb1[hf*6 + kk];
            float w;
            w = wrp[(4*kk  )*32]; ar0 = fmaf(w, c0.x, ar0); ar1 = fmaf(w, c1.x, ar1);
            w = wrp[(4*kk+1)*32]; ar0 = fmaf(w, c0.y, ar0); ar1 = fmaf(w, c1.y, ar1);
            w = wrp[(4*kk+2)*32]; ar0 = fmaf(w, c0.z, ar0); ar1 = fmaf(w, c1.z, ar1);
            w = wrp[(4*kk+3)*32]; ar0 = fmaf(w, c0.w, ar0); ar1 = fmaf(w, c1.w, ar1);
            w = wzp[(4*kk  )*32]; az0 = fmaf(w, c0.x, az0); az1 = fmaf(w, c1.x, az1);
            w = wzp[(4*kk+1)*32]; az0 = fmaf(w, c0.y, az0); az1 = fmaf(w, c1.y, az1);
            w = wzp[(4*kk+2)*32]; az0 = fmaf(w, c0.z, az0); az1 = fmaf(w, c1.z, az1);
            w = wzp[(4*kk+3)*32]; az0 = fmaf(w, c0.w, az0); az1 = fmaf(w, c1.w, az1);
        }
        float in0 = 0.f, in1 = 0.f, hn0 = 0.f, hn1 = 0.f;
        #pragma unroll
        for (int kk = 0; kk < 4; ++kk) {
            float4 c0 = bb0[kk];
            float4 c1 = bb1[kk];
            float w;
            w = wnip[(4*kk  )*32]; in0 = fmaf(w, c0.x, in0); in1 = fmaf(w, c1.x, in1);
            w = wnip[(4*kk+1)*32]; in0 = fmaf(w, c0.y, in0); in1 = fmaf(w, c1.y, in1);
            w = wnip[(4*kk+2)*32]; in0 = fmaf(w, c0.z, in0); in1 = fmaf(w, c1.z, in1);
            w = wnip[(4*kk+3)*32]; in0 = fmaf(w, c0.w, in0); in1 = fmaf(w, c1.w, in1);
        }
        #pragma unroll
        for (int kk = 0; kk < 4; ++kk) {
            float4 c0 = bb0[4 + hf*4 + kk];
            float4 c1 = bb1[4 + hf*4 + kk];
            float w;
            w = wnhp[(4*kk  )*32]; hn0 = fmaf(w, c0.x, hn0); hn1 = fmaf(w, c1.x, hn1);
            w = wnhp[(4*kk+1)*32]; hn0 = fmaf(w, c0.y, hn0); hn1 = fmaf(w, c1.y, hn1);
            w = wnhp[(4*kk+2)*32]; hn0 = fmaf(w, c0.z, hn0); hn1 = fmaf(w, c1.z, hn1);
            w = wnhp[(4*kk+3)*32]; hn0 = fmaf(w, c0.w, hn0); hn1 = fmaf(w, c1.w, hn1);
        }
        ar0 = xhsum(ar0) + brr;  ar1 = xhsum(ar1) + brr;
        az0 = xhsum(az0) + bzz;  az1 = xhsum(az1) + bzz;
        hn0 = xhsum(hn0) + bhn;  hn1 = xhsum(hn1) + bhn;
        in0 += bin;              in1 += bin;

        float rg0 = 1.0f / (1.0f + __expf(-ar0));
        float rg1 = 1.0f / (1.0f + __expf(-ar1));
        float zg0 = 1.0f / (1.0f + __expf(-az0));
        float zg1 = 1.0f / (1.0f + __expf(-az1));
        float ng0 = tanhf(fmaf(rg0, hn0, in0));
        float ng1 = tanhf(fmaf(rg1, hn1, in1));
        outv0 = (1.0f - zg0) * ng0 + zg0 * hv0;
        outv1 = (1.0f - zg1) * ng1 + zg1 * hv1;

        hv0 = outv0;
        hv1 = outv1;
        if (s < NS - 2) {   // final step's ODE integration is dead -> skip
            const float ddt0 = (t[(size_t)b0 * NS + s + 1] - t[(size_t)b0 * NS + s]) * 0.25f;
            const float ddt1 = (t[(size_t)b1 * NS + s + 1] - t[(size_t)b1 * NS + s]) * 0.25f;
            float hi0 = outv0, hi1 = outv1;
            #pragma unroll 1
            for (int sub = 0; sub < 4; ++sub) {
                float k1_0, k1_1, k2_0, k2_1, k3_0, k3_1,
                      k4_0, k4_1, k5_0, k5_1, k6_0, k6_1;
                ode_f2(hi0, hi1, k1_0, k1_1);
                ode_f2(fmaf(ddt0, 0.2f * k1_0, hi0),
                       fmaf(ddt1, 0.2f * k1_1, hi1), k2_0, k2_1);
                ode_f2(fmaf(ddt0, fmaf((float)(9.0/40.0), k2_0, (float)(3.0/40.0) * k1_0), hi0),
                       fmaf(ddt1, fmaf((float)(9.0/40.0), k2_1, (float)(3.0/40.0) * k1_1), hi1),
                       k3_0, k3_1);
                ode_f2(fmaf(ddt0, fmaf((float)(32.0/9.0), k3_0,
                                  fmaf(-(float)(56.0/15.0), k2_0, (float)(44.0/45.0) * k1_0)), hi0),
                       fmaf(ddt1, fmaf((float)(32.0/9.0), k3_1,
                                  fmaf(-(float)(56.0/15.0), k2_1, (float)(44.0/45.0) * k1_1)), hi1),
                       k4_0, k4_1);
                ode_f2(fmaf(ddt0, fmaf(-(float)(212.0/729.0), k4_0,
                                  fmaf((float)(64448.0/6561.0), k3_0,
                                  fmaf(-(float)(25360.0/2187.0), k2_0, (float)(19372.0/6561.0) * k1_0))), hi0),
                       fmaf(ddt1, fmaf(-(float)(212.0/729.0), k4_1,
                                  fmaf((float)(64448.0/6561.0), k3_1,
                                  fmaf(-(float)(25360.0/2187.0), k2_1, (float)(19372.0/6561.0) * k1_1))), hi1),
                       k5_0, k5_1);
                ode_f2(fmaf(ddt0, fmaf(-(float)(5103.0/18656.0), k5_0,
                                  fmaf((float)(49.0/176.0), k4_0,
                                  fmaf((float)(46732.0/5247.0), k3_0,
                                  fmaf(-(float)(355.0/33.0), k2_0, (float)(9017.0/3168.0) * k1_0)))), hi0),
                       fmaf(ddt1, fmaf(-(float)(5103.0/18656.0), k5_1,
                                  fmaf((float)(49.0/176.0), k4_1,
                                  fmaf((float)(46732.0/5247.0), k3_1,
                                  fmaf(-(float)(355.0/33.0), k2_1, (float)(9017.0/3168.0) * k1_1)))), hi1),
                       k6_0, k6_1);
                hi0 = fmaf(ddt0, fmaf((float)(11.0/84.0), k6_0,
                                 fmaf(-(float)(2187.0/6784.0), k5_0,
                                 fmaf((float)(125.0/192.0), k4_0,
                                 fmaf((float)(500.0/1113.0), k3_0, (float)(35.0/384.0) * k1_0)))), hi0);
                hi1 = fmaf(ddt1, fmaf((float)(11.0/84.0), k6_1,
                                 fmaf(-(float)(2187.0/6784.0), k5_1,
                                 fmaf((float)(125.0/192.0), k4_1,
                                 fmaf((float)(500.0/1113.0), k3_1, (float)(35.0/384.0) * k1_1)))), hi1);
            }
            hv0 = hi0;
            hv1 = hi1;
        }
    }

    // ---------- FC head: relu(out @ fW1.T + fb1) @ fW2.T + fb2 ----------
    bufw0[hf * 32 + r] = outv0;
    bufw1[hf * 32 + r] = outv1;
    fence();
    f32x2 acc0 = f32x2{fb1[lane], 0.0f};
    f32x2 acc1h = f32x2{fb1[lane], 0.0f};
    {
        const float4* fw = reinterpret_cast<const float4*>(fW1) + lane * 8;
        #pragma unroll
        for (int kk = 0; kk < 8; ++kk) {
            float4 wv = fw[kk];
            float4 c0 = bb0[kk];
            float4 c1 = bb1[kk];
            acc0  = pkfma(f32x2{wv.x, wv.y}, f32x2{c0.x, c0.y}, acc0);
            acc0  = pkfma(f32x2{wv.z, wv.w}, f32x2{c0.z, c0.w}, acc0);
            acc1h = pkfma(f32x2{wv.x, wv.y}, f32x2{c1.x, c1.y}, acc1h);
            acc1h = pkfma(f32x2{wv.z, wv.w}, f32x2{c1.z, c1.w}, acc1h);
        }
    }
    float fw2v = fW2[lane];
    float pa = fmaxf(acc0.x + acc0.y, 0.0f) * fw2v;
    float pb = fmaxf(acc1h.x + acc1h.y, 0.0f) * fw2v;
    #pragma unroll
    for (int m = 1; m < 64; m <<= 1) {
        pa += __shfl_xor(pa, m, 64);
        pb += __shfl_xor(pb, m, 64);
    }
    if (lane == 0) {
        float bias = fb2[0];
        outp[b0] = pa + bias;
        outp[b1] = pb + bias;
    }
}

extern "C" void kernel_launch(void* const* d_in, const int* in_sizes, int n_in,
                              void* d_out, int out_size, void* d_ws, size_t ws_size,
                              hipStream_t stream) {
    (void)in_sizes; (void)n_in; (void)d_ws; (void)ws_size; (void)out_size;
    odernn_kernel<<<dim3(NB / 8), dim3(256), 0, stream>>>(
        (const float*)d_in[0],  (const float*)d_in[1],
        (const float*)d_in[2],  (const float*)d_in[3],
        (const float*)d_in[4],  (const float*)d_in[5],
        (const float*)d_in[6],  (const float*)d_in[7],
        (const float*)d_in[8],  (const float*)d_in[9],
        (const float*)d_in[10], (const float*)d_in[11],
        (const float*)d_in[12], (const float*)d_in[13],
        (const float*)d_in[14], (const float*)d_in[15],
        (float*)d_out);
}